// Round 1
// baseline (1591.749 us; speedup 1.0000x reference)
//
#include <hip/hip_runtime.h>
#include <math.h>

#define N_NODES 100000
#define N_EDGES 1600000
#define D 128
#define NCLASS 10
#define NLAYERS 3
#define BN_EPS 1e-5f

#define GP 132   // padded LDS row stride (floats) for gemm tiles (16B-aligned, breaks pow2)

// ---------------- CSR build ----------------
__global__ void k_count(const int* __restrict__ dst, int* __restrict__ counts) {
    int e = blockIdx.x * 256 + threadIdx.x;
    if (e < N_EDGES) atomicAdd(&counts[dst[e]], 1);
}

__global__ void k_scan_a(const int* __restrict__ counts, int* __restrict__ bsums) {
    __shared__ int sh[256];
    int t = threadIdx.x;
    int i = blockIdx.x * 512 + 2 * t;
    int s = 0;
    if (i < N_NODES) s += counts[i];
    if (i + 1 < N_NODES) s += counts[i + 1];
    sh[t] = s; __syncthreads();
    for (int off = 128; off > 0; off >>= 1) {
        if (t < off) sh[t] += sh[t + off];
        __syncthreads();
    }
    if (t == 0) bsums[blockIdx.x] = sh[0];
}

__global__ void k_scan_b(const int* __restrict__ bsums, int* __restrict__ boffs,
                         int* __restrict__ row_ptr, int nb) {
    __shared__ int sh[256];
    int t = threadIdx.x;
    int v = (t < nb) ? bsums[t] : 0;
    sh[t] = v; __syncthreads();
    for (int off = 1; off < 256; off <<= 1) {
        int add = (t >= off) ? sh[t - off] : 0;
        __syncthreads();
        sh[t] += add;
        __syncthreads();
    }
    if (t < nb) boffs[t] = sh[t] - v;       // exclusive
    if (t == 255) row_ptr[N_NODES] = sh[255];
}

__global__ void k_scan_c(const int* __restrict__ counts, const int* __restrict__ boffs,
                         int* __restrict__ row_ptr) {
    __shared__ int sh[256];
    int b = blockIdx.x, t = threadIdx.x;
    int i = b * 512 + 2 * t;
    int c0 = (i < N_NODES) ? counts[i] : 0;
    int c1 = (i + 1 < N_NODES) ? counts[i + 1] : 0;
    int s = c0 + c1;
    sh[t] = s; __syncthreads();
    for (int off = 1; off < 256; off <<= 1) {
        int add = (t >= off) ? sh[t - off] : 0;
        __syncthreads();
        sh[t] += add;
        __syncthreads();
    }
    int excl = sh[t] - s + boffs[b];
    if (i < N_NODES) row_ptr[i] = excl;
    if (i + 1 < N_NODES) row_ptr[i + 1] = excl + c0;
}

__global__ void k_fill(const int* __restrict__ src, const int* __restrict__ dst,
                       const int* __restrict__ row_ptr, int* __restrict__ cursor,
                       int* __restrict__ csr) {
    int e = blockIdx.x * 256 + threadIdx.x;
    if (e < N_EDGES) {
        int d = dst[e];
        int pos = atomicAdd(&cursor[d], 1);
        csr[row_ptr[d] + pos] = src[e];
    }
}

// ---------------- aggregation: out[i] = h[i] + sum_{j in-neighbors} h[j] ----------------
__global__ __launch_bounds__(256) void k_aggregate(const float* __restrict__ h,
                                                   const int* __restrict__ row_ptr,
                                                   const int* __restrict__ csr,
                                                   float* __restrict__ out) {
    int node = blockIdx.x * 4 + (threadIdx.x >> 6);
    int lane = threadIdx.x & 63;
    if (node >= N_NODES) return;
    const float2* hp = (const float2*)h;
    float2 acc = hp[node * 64 + lane];
    int e0 = row_ptr[node], e1 = row_ptr[node + 1];
    for (int e = e0; e < e1; ++e) {
        int j = csr[e];
        float2 v = hp[j * 64 + lane];
        acc.x += v.x; acc.y += v.y;
    }
    ((float2*)out)[node * 64 + lane] = acc;
}

// ---------------- fused GEMM: out[r][f] = post( sum_k pre(in[r][k]) * W[f][k] + bias[f] ) ----
// PRE: 0 = identity, 1 = relu(x*scale[k]+shift[k])   POST: 0 = none, 1 = relu
template <int PRE, int POST>
__global__ __launch_bounds__(256) void k_gemm(const float* __restrict__ in,
                                              const float* __restrict__ W,
                                              const float* __restrict__ bias,
                                              const float* __restrict__ scale,
                                              const float* __restrict__ shift,
                                              float* __restrict__ out, int nrows) {
    __shared__ float sA[128 * GP];   // sA[k*GP + r]  (input tile, transposed)
    __shared__ float sB[128 * GP];   // sB[k*GP + f]  (weights, transposed)
    __shared__ float sb[128];

    int t = threadIdx.x;
    int r0blk = blockIdx.x * 128;

    // stage W transposed: W[f][k] -> sB[k][f]
    for (int idx = t; idx < 128 * 32; idx += 256) {
        int f = idx >> 5, c4 = (idx & 31) * 4;
        float4 v = *(const float4*)(W + f * 128 + c4);
        sB[(c4 + 0) * GP + f] = v.x;
        sB[(c4 + 1) * GP + f] = v.y;
        sB[(c4 + 2) * GP + f] = v.z;
        sB[(c4 + 3) * GP + f] = v.w;
    }
    if (t < 128) sb[t] = bias[t];

    // stage input tile transposed (with optional BN+relu prologue)
    for (int idx = t; idx < 128 * 32; idx += 256) {
        int r = idx >> 5, c4 = (idx & 31) * 4;
        int rr = r0blk + r;
        float4 v;
        if (rr < nrows) v = *(const float4*)(in + (size_t)rr * 128 + c4);
        else            v = make_float4(0.f, 0.f, 0.f, 0.f);
        if (PRE == 1) {
            v.x = fmaxf(fmaf(v.x, scale[c4 + 0], shift[c4 + 0]), 0.f);
            v.y = fmaxf(fmaf(v.y, scale[c4 + 1], shift[c4 + 1]), 0.f);
            v.z = fmaxf(fmaf(v.z, scale[c4 + 2], shift[c4 + 2]), 0.f);
            v.w = fmaxf(fmaf(v.w, scale[c4 + 3], shift[c4 + 3]), 0.f);
        }
        sA[(c4 + 0) * GP + r] = v.x;
        sA[(c4 + 1) * GP + r] = v.y;
        sA[(c4 + 2) * GP + r] = v.z;
        sA[(c4 + 3) * GP + r] = v.w;
    }
    __syncthreads();

    int tc = t & 15, tr = t >> 4;
    int rbase = tr * 8, cbase = tc * 8;

    float acc[8][8];
#pragma unroll
    for (int i = 0; i < 8; ++i)
#pragma unroll
        for (int j = 0; j < 8; ++j) acc[i][j] = 0.f;

#pragma unroll 4
    for (int k = 0; k < 128; ++k) {
        float4 a0 = *(const float4*)&sA[k * GP + rbase];
        float4 a1 = *(const float4*)&sA[k * GP + rbase + 4];
        float4 b0 = *(const float4*)&sB[k * GP + cbase];
        float4 b1 = *(const float4*)&sB[k * GP + cbase + 4];
        float a[8] = {a0.x, a0.y, a0.z, a0.w, a1.x, a1.y, a1.z, a1.w};
        float b[8] = {b0.x, b0.y, b0.z, b0.w, b1.x, b1.y, b1.z, b1.w};
#pragma unroll
        for (int i = 0; i < 8; ++i)
#pragma unroll
            for (int j = 0; j < 8; ++j)
                acc[i][j] = fmaf(a[i], b[j], acc[i][j]);
    }

#pragma unroll
    for (int i = 0; i < 8; ++i) {
        int rr = r0blk + rbase + i;
        if (rr < nrows) {
            float o[8];
#pragma unroll
            for (int j = 0; j < 8; ++j) {
                o[j] = acc[i][j] + sb[cbase + j];
                if (POST == 1) o[j] = fmaxf(o[j], 0.f);
            }
            *(float4*)(out + (size_t)rr * 128 + cbase)     = make_float4(o[0], o[1], o[2], o[3]);
            *(float4*)(out + (size_t)rr * 128 + cbase + 4) = make_float4(o[4], o[5], o[6], o[7]);
        }
    }
}

// ---------------- BN statistics ----------------
__global__ __launch_bounds__(256) void k_stats(const float* __restrict__ z,
                                               float* __restrict__ gsum,
                                               float* __restrict__ gsq) {
    int col = threadIdx.x & 127;
    int half = threadIdx.x >> 7;  // 0 or 1
    int r0 = blockIdx.x * 500 + half;
    int rend = blockIdx.x * 500 + 500;
    float s = 0.f, q = 0.f;
    for (int r = r0; r < rend; r += 2) {
        float v = z[(size_t)r * 128 + col];
        s += v; q += v * v;
    }
    atomicAdd(&gsum[col], s);
    atomicAdd(&gsq[col], q);
}

__global__ void k_bnfin(const float* __restrict__ gsum, const float* __restrict__ gsq,
                        const float* __restrict__ gamma, const float* __restrict__ beta,
                        float* __restrict__ scale, float* __restrict__ shift) {
    int d = threadIdx.x;
    float mu = gsum[d] * (1.f / N_NODES);
    float var = gsq[d] * (1.f / N_NODES) - mu * mu;
    float rstd = rsqrtf(var + BN_EPS);
    float sc = rstd * gamma[d];
    scale[d] = sc;
    shift[d] = beta[d] - mu * sc;
}

// ---------------- head: out = sigmoid(tin @ lin2_W.T + lin2_b) ----------------
__global__ __launch_bounds__(128) void k_head2(const float* __restrict__ tin,
                                               const float* __restrict__ W2,
                                               const float* __restrict__ b2,
                                               float* __restrict__ out) {
    __shared__ float sh[128 * 130];     // rows, stride 130 (2-way bank alias = free)
    __shared__ float w2s[NCLASS * 128];
    __shared__ float b2s[NCLASS];
    int t = threadIdx.x;
    int r0 = blockIdx.x * 128;

    for (int idx = t; idx < (NCLASS * 128) / 4; idx += 128) {
        float4 v = *(const float4*)(W2 + idx * 4);
        *(float4*)&w2s[idx * 4] = v;
    }
    if (t < NCLASS) b2s[t] = b2[t];

    const float2* tp = (const float2*)tin;
    for (int idx = t; idx < 128 * 64; idx += 128) {
        int r = idx >> 6, c2 = idx & 63;
        int rr = r0 + r;
        float2 v = (rr < N_NODES) ? tp[(size_t)rr * 64 + c2] : make_float2(0.f, 0.f);
        *(float2*)&sh[r * 130 + c2 * 2] = v;
    }
    __syncthreads();

    float acc[NCLASS];
#pragma unroll
    for (int c = 0; c < NCLASS; ++c) acc[c] = 0.f;
    const float* myrow = &sh[t * 130];
#pragma unroll 4
    for (int k = 0; k < 128; ++k) {
        float v = myrow[k];
#pragma unroll
        for (int c = 0; c < NCLASS; ++c)
            acc[c] = fmaf(v, w2s[c * 128 + k], acc[c]);
    }
    int rr = r0 + t;
    if (rr < N_NODES) {
#pragma unroll
        for (int c = 0; c < NCLASS; ++c) {
            float z = acc[c] + b2s[c];
            out[(size_t)rr * NCLASS + c] = 1.f / (1.f + expf(-z));
        }
    }
}

// ---------------- launcher ----------------
extern "C" void kernel_launch(void* const* d_in, const int* in_sizes, int n_in,
                              void* d_out, int out_size, void* d_ws, size_t ws_size,
                              hipStream_t stream) {
    const float* x     = (const float*)d_in[0];
    const int*   ei    = (const int*)d_in[1];
    const float* W1    = (const float*)d_in[2];
    const float* b1    = (const float*)d_in[3];
    const float* gamma = (const float*)d_in[4];
    const float* beta  = (const float*)d_in[5];
    const float* W2    = (const float*)d_in[6];
    const float* b2    = (const float*)d_in[7];
    const float* l1W   = (const float*)d_in[8];
    const float* l1b   = (const float*)d_in[9];
    const float* l2W   = (const float*)d_in[10];
    const float* l2b   = (const float*)d_in[11];
    float* out = (float*)d_out;

    char* w = (char*)d_ws;
    float* bufA   = (float*)(w);                    // 51,200,000 B
    float* bufB   = (float*)(w + 51200000);         // 51,200,000 B
    int*   row_ptr= (int*)  (w + 102400000);        // 400,004 B (reserve 400,640)
    int*   counts = (int*)  (w + 102800640);        // 400,000 B
    int*   csr    = (int*)  (w + 103200640);        // 6,400,000 B
    int*   bsums  = (int*)  (w + 109600640);        // 784 B (reserve 1024)
    int*   boffs  = (int*)  (w + 109601664);        // 784 B (reserve 1024)
    float* gsum   = (float*)(w + 109602688);        // 4*128 floats
    float* gsq    = gsum + 128;
    float* scale  = gsum + 256;
    float* shift  = gsum + 384;

    const int* src = ei;
    const int* dst = ei + N_EDGES;

    const int SCAN_NB = (N_NODES + 511) / 512;      // 196
    const int GEMM_NB = (N_NODES + 127) / 128;      // 782

    // ---- CSR build (once per call) ----
    hipMemsetAsync(counts, 0, N_NODES * sizeof(int), stream);
    k_count<<<(N_EDGES + 255) / 256, 256, 0, stream>>>(dst, counts);
    k_scan_a<<<SCAN_NB, 256, 0, stream>>>(counts, bsums);
    k_scan_b<<<1, 256, 0, stream>>>(bsums, boffs, row_ptr, SCAN_NB);
    k_scan_c<<<SCAN_NB, 256, 0, stream>>>(counts, boffs, row_ptr);
    hipMemsetAsync(counts, 0, N_NODES * sizeof(int), stream);   // reuse as cursor
    k_fill<<<(N_EDGES + 255) / 256, 256, 0, stream>>>(src, dst, row_ptr, counts, csr);

    // ---- 3 GIN layers ----
    for (int l = 0; l < NLAYERS; ++l) {
        const float* hin = (l == 0) ? x : bufA;
        k_aggregate<<<N_NODES / 4, 256, 0, stream>>>(hin, row_ptr, csr, bufB);
        // z = (h+agg) @ W1.T + b1   (in-place on bufB)
        k_gemm<0, 0><<<GEMM_NB, 256, 0, stream>>>(bufB, W1 + l * D * D, b1 + l * D,
                                                  nullptr, nullptr, bufB, N_NODES);
        hipMemsetAsync(gsum, 0, 256 * sizeof(float), stream);
        k_stats<<<200, 256, 0, stream>>>(bufB, gsum, gsq);
        k_bnfin<<<1, 128, 0, stream>>>(gsum, gsq, gamma + l * D, beta + l * D, scale, shift);
        // h' = relu( relu(BN(z)) @ W2.T + b2 )
        k_gemm<1, 1><<<GEMM_NB, 256, 0, stream>>>(bufB, W2 + l * D * D, b2 + l * D,
                                                  scale, shift, bufA, N_NODES);
    }

    // ---- head ----
    k_gemm<0, 1><<<GEMM_NB, 256, 0, stream>>>(bufA, l1W, l1b, nullptr, nullptr, bufB, N_NODES);
    k_head2<<<GEMM_NB, 128, 0, stream>>>(bufB, l2W, l2b, out);
}

// Round 2
// 736.055 us; speedup vs baseline: 2.1625x; 2.1625x over previous
//
#include <hip/hip_runtime.h>
#include <math.h>

#define N_NODES 100000
#define N_EDGES 1600000
#define D 128
#define NCLASS 10
#define NLAYERS 3
#define BN_EPS 1e-5f

#define LDA 136   // padded LDS row stride in bf16 elems (272 B -> uniform bank spread)

typedef __attribute__((ext_vector_type(8))) short bf16x8;
typedef __attribute__((ext_vector_type(4))) float f32x4;

__device__ __forceinline__ ushort f2b(float x) {          // RNE fp32 -> bf16
    uint u = __float_as_uint(x);
    return (ushort)((u + 0x7fffu + ((u >> 16) & 1u)) >> 16);
}
__device__ __forceinline__ float b2f(uint u) {            // bf16 bits -> fp32 (exact)
    return __uint_as_float(u << 16);
}
__device__ __forceinline__ uint pack2(float a, float b) {
    return (uint)f2b(a) | ((uint)f2b(b) << 16);
}

// ---------------- CSR build ----------------
__global__ void k_count(const int* __restrict__ dst, int* __restrict__ counts) {
    int e = blockIdx.x * 256 + threadIdx.x;
    if (e < N_EDGES) atomicAdd(&counts[dst[e]], 1);
}

__global__ void k_scan_a(const int* __restrict__ counts, int* __restrict__ bsums) {
    __shared__ int sh[256];
    int t = threadIdx.x;
    int i = blockIdx.x * 512 + 2 * t;
    int s = 0;
    if (i < N_NODES) s += counts[i];
    if (i + 1 < N_NODES) s += counts[i + 1];
    sh[t] = s; __syncthreads();
    for (int off = 128; off > 0; off >>= 1) {
        if (t < off) sh[t] += sh[t + off];
        __syncthreads();
    }
    if (t == 0) bsums[blockIdx.x] = sh[0];
}

__global__ void k_scan_b(const int* __restrict__ bsums, int* __restrict__ boffs,
                         int* __restrict__ row_ptr, int nb) {
    __shared__ int sh[256];
    int t = threadIdx.x;
    int v = (t < nb) ? bsums[t] : 0;
    sh[t] = v; __syncthreads();
    for (int off = 1; off < 256; off <<= 1) {
        int add = (t >= off) ? sh[t - off] : 0;
        __syncthreads();
        sh[t] += add;
        __syncthreads();
    }
    if (t < nb) boffs[t] = sh[t] - v;
    if (t == 255) row_ptr[N_NODES] = sh[255];
}

__global__ void k_scan_c(const int* __restrict__ counts, const int* __restrict__ boffs,
                         int* __restrict__ row_ptr) {
    __shared__ int sh[256];
    int b = blockIdx.x, t = threadIdx.x;
    int i = b * 512 + 2 * t;
    int c0 = (i < N_NODES) ? counts[i] : 0;
    int c1 = (i + 1 < N_NODES) ? counts[i + 1] : 0;
    int s = c0 + c1;
    sh[t] = s; __syncthreads();
    for (int off = 1; off < 256; off <<= 1) {
        int add = (t >= off) ? sh[t - off] : 0;
        __syncthreads();
        sh[t] += add;
        __syncthreads();
    }
    int excl = sh[t] - s + boffs[b];
    if (i < N_NODES) row_ptr[i] = excl;
    if (i + 1 < N_NODES) row_ptr[i + 1] = excl + c0;
}

__global__ void k_fill(const int* __restrict__ src, const int* __restrict__ dst,
                       const int* __restrict__ row_ptr, int* __restrict__ cursor,
                       int* __restrict__ csr) {
    int e = blockIdx.x * 256 + threadIdx.x;
    if (e < N_EDGES) {
        int d = dst[e];
        int pos = atomicAdd(&cursor[d], 1);
        csr[row_ptr[d] + pos] = src[e];
    }
}

// ---------------- fp32 -> bf16 bulk convert ----------------
__global__ void k_tobf16(const float* __restrict__ x, ushort* __restrict__ o) {
    int i = blockIdx.x * 256 + threadIdx.x;   // one float4 per thread
    const int n4 = N_NODES * D / 4;
    if (i < n4) {
        float4 v = ((const float4*)x)[i];
        uint2 u;
        u.x = pack2(v.x, v.y);
        u.y = pack2(v.z, v.w);
        ((uint2*)o)[i] = u;
    }
}

// ---------------- aggregation (bf16 gather, fp32 accum, bf16 out) ----------------
__global__ __launch_bounds__(256) void k_aggregate(const ushort* __restrict__ hbf,
                                                   const int* __restrict__ row_ptr,
                                                   const int* __restrict__ csr,
                                                   ushort* __restrict__ outbf) {
    int node = blockIdx.x * 4 + (threadIdx.x >> 6);
    int lane = threadIdx.x & 63;
    const uint* hp = (const uint*)hbf;
    uint self = hp[(size_t)node * 64 + lane];
    float ax = b2f(self & 0xffffu), ay = b2f(self >> 16);
    int e0 = row_ptr[node], e1 = row_ptr[node + 1];
    int e = e0;
    for (; e + 3 < e1; e += 4) {
        int j0 = csr[e], j1 = csr[e + 1], j2 = csr[e + 2], j3 = csr[e + 3];
        uint v0 = hp[(size_t)j0 * 64 + lane];
        uint v1 = hp[(size_t)j1 * 64 + lane];
        uint v2 = hp[(size_t)j2 * 64 + lane];
        uint v3 = hp[(size_t)j3 * 64 + lane];
        ax += b2f(v0 & 0xffffu); ay += b2f(v0 >> 16);
        ax += b2f(v1 & 0xffffu); ay += b2f(v1 >> 16);
        ax += b2f(v2 & 0xffffu); ay += b2f(v2 >> 16);
        ax += b2f(v3 & 0xffffu); ay += b2f(v3 >> 16);
    }
    for (; e < e1; ++e) {
        int j = csr[e];
        uint v = hp[(size_t)j * 64 + lane];
        ax += b2f(v & 0xffffu); ay += b2f(v >> 16);
    }
    ((uint*)outbf)[(size_t)node * 64 + lane] = pack2(ax, ay);
}

// ---------------- MFMA GEMM: out[r][f] = post( sum_k pre(in[r][k]) * W[f][k] + bias[f] ) ----
// PRE: 0 = A is bf16, copy; 1 = A is fp32 z, apply relu(z*scale+shift), cvt bf16
// POST: 1 = relu.  OUTBF: 1 = write bf16, else fp32.  STATS: column sum/sumsq atomics.
template <int PRE, int POST, int OUTBF, int STATS>
__global__ __launch_bounds__(256, 2) void k_gemm(const void* __restrict__ inA,
                                                 const float* __restrict__ W,
                                                 const float* __restrict__ bias,
                                                 const float* __restrict__ scale,
                                                 const float* __restrict__ shift,
                                                 void* __restrict__ outp,
                                                 float* __restrict__ gsum,
                                                 float* __restrict__ gsq,
                                                 int nrows) {
    __shared__ ushort sA[128 * LDA];
    __shared__ ushort sB[128 * LDA];
    __shared__ float sbias[128];

    int t = threadIdx.x;
    int r0 = blockIdx.x * 128;

    // stage W [f][k] fp32 -> bf16 LDS
    for (int idx = t; idx < 128 * 32; idx += 256) {
        int f = idx >> 5, c4 = (idx & 31) << 2;
        float4 v = *(const float4*)(W + f * 128 + c4);
        ushort4 u;
        u.x = f2b(v.x); u.y = f2b(v.y); u.z = f2b(v.z); u.w = f2b(v.w);
        *(ushort4*)&sB[f * LDA + c4] = u;
    }
    if (t < 128) sbias[t] = bias[t];

    if (PRE == 0) {
        const ushort* A = (const ushort*)inA;
        for (int idx = t; idx < 128 * 16; idx += 256) {
            int r = idx >> 4, c8 = (idx & 15) << 3;
            int rr = r0 + r;
            uint4 v = make_uint4(0u, 0u, 0u, 0u);
            if (rr < nrows) v = *(const uint4*)(A + (size_t)rr * 128 + c8);
            *(uint4*)&sA[r * LDA + c8] = v;
        }
    } else {
        const float* A = (const float*)inA;
        for (int idx = t; idx < 128 * 32; idx += 256) {
            int r = idx >> 5, c4 = (idx & 31) << 2;
            int rr = r0 + r;
            float4 v = make_float4(0.f, 0.f, 0.f, 0.f);
            if (rr < nrows) v = *(const float4*)(A + (size_t)rr * 128 + c4);
            float4 sc = *(const float4*)(scale + c4);
            float4 sf = *(const float4*)(shift + c4);
            v.x = fmaxf(fmaf(v.x, sc.x, sf.x), 0.f);
            v.y = fmaxf(fmaf(v.y, sc.y, sf.y), 0.f);
            v.z = fmaxf(fmaf(v.z, sc.z, sf.z), 0.f);
            v.w = fmaxf(fmaf(v.w, sc.w, sf.w), 0.f);
            ushort4 u;
            u.x = f2b(v.x); u.y = f2b(v.y); u.z = f2b(v.z); u.w = f2b(v.w);
            *(ushort4*)&sA[r * LDA + c4] = u;
        }
    }
    __syncthreads();

    int lane = t & 63, wid = t >> 6;
    int rl = lane & 15, g = lane >> 4;
    int wr = wid >> 1, wc = wid & 1;

    f32x4 acc[4][4];
#pragma unroll
    for (int i = 0; i < 4; ++i)
#pragma unroll
        for (int j = 0; j < 4; ++j) acc[i][j] = (f32x4){0.f, 0.f, 0.f, 0.f};

#pragma unroll
    for (int ks = 0; ks < 4; ++ks) {
        int koff = ks * 32 + g * 8;
        bf16x8 a[4], b[4];
#pragma unroll
        for (int mi = 0; mi < 4; ++mi)
            a[mi] = *(const bf16x8*)&sA[(wr * 64 + mi * 16 + rl) * LDA + koff];
#pragma unroll
        for (int ni = 0; ni < 4; ++ni)
            b[ni] = *(const bf16x8*)&sB[(wc * 64 + ni * 16 + rl) * LDA + koff];
#pragma unroll
        for (int mi = 0; mi < 4; ++mi)
#pragma unroll
            for (int ni = 0; ni < 4; ++ni)
                acc[mi][ni] = __builtin_amdgcn_mfma_f32_16x16x32_bf16(a[mi], b[ni], acc[mi][ni], 0, 0, 0);
    }

    // epilogue
    float bn[4], ssum[4], ssq[4];
#pragma unroll
    for (int ni = 0; ni < 4; ++ni) {
        bn[ni] = sbias[wc * 64 + ni * 16 + rl];
        ssum[ni] = 0.f; ssq[ni] = 0.f;
    }

#pragma unroll
    for (int mi = 0; mi < 4; ++mi) {
        int orow = r0 + wr * 64 + mi * 16 + g * 4;
#pragma unroll
        for (int j = 0; j < 4; ++j) {
            int row = orow + j;
            if (row < nrows) {
#pragma unroll
                for (int ni = 0; ni < 4; ++ni) {
                    int ocol = wc * 64 + ni * 16 + rl;
                    float o = acc[mi][ni][j] + bn[ni];
                    if (STATS) { ssum[ni] += o; ssq[ni] += o * o; }
                    if (POST) o = fmaxf(o, 0.f);
                    if (OUTBF) ((ushort*)outp)[(size_t)row * 128 + ocol] = f2b(o);
                    else       ((float*)outp)[(size_t)row * 128 + ocol] = o;
                }
            }
        }
    }

    if (STATS) {
#pragma unroll
        for (int ni = 0; ni < 4; ++ni) {
            float s = ssum[ni], q = ssq[ni];
            s += __shfl_xor(s, 16, 64); q += __shfl_xor(q, 16, 64);
            s += __shfl_xor(s, 32, 64); q += __shfl_xor(q, 32, 64);
            if (g == 0) {
                int col = wc * 64 + ni * 16 + rl;
                atomicAdd(&gsum[col], s);
                atomicAdd(&gsq[col], q);
            }
        }
    }
}

// ---------------- BN finalize ----------------
__global__ void k_bnfin(const float* __restrict__ gsum, const float* __restrict__ gsq,
                        const float* __restrict__ gamma, const float* __restrict__ beta,
                        float* __restrict__ scale, float* __restrict__ shift) {
    int d = threadIdx.x;
    float mu = gsum[d] * (1.f / N_NODES);
    float var = gsq[d] * (1.f / N_NODES) - mu * mu;
    float rstd = rsqrtf(var + BN_EPS);
    float sc = rstd * gamma[d];
    scale[d] = sc;
    shift[d] = beta[d] - mu * sc;
}

// ---------------- head: out = sigmoid(tin @ lin2_W.T + lin2_b), tin bf16 ----------------
__global__ __launch_bounds__(128) void k_head2(const ushort* __restrict__ tin,
                                               const float* __restrict__ W2,
                                               const float* __restrict__ b2,
                                               float* __restrict__ out) {
    __shared__ float sh[128 * 130];
    __shared__ float w2s[NCLASS * 128];
    __shared__ float b2s[NCLASS];
    int t = threadIdx.x;
    int r0 = blockIdx.x * 128;

    for (int idx = t; idx < (NCLASS * 128) / 4; idx += 128) {
        float4 v = *(const float4*)(W2 + idx * 4);
        *(float4*)&w2s[idx * 4] = v;
    }
    if (t < NCLASS) b2s[t] = b2[t];

    const uint* tp = (const uint*)tin;
    for (int idx = t; idx < 128 * 64; idx += 128) {
        int r = idx >> 6, c2 = idx & 63;
        int rr = r0 + r;
        uint v = (rr < N_NODES) ? tp[(size_t)rr * 64 + c2] : 0u;
        sh[r * 130 + 2 * c2]     = b2f(v & 0xffffu);
        sh[r * 130 + 2 * c2 + 1] = b2f(v >> 16);
    }
    __syncthreads();

    float acc[NCLASS];
#pragma unroll
    for (int c = 0; c < NCLASS; ++c) acc[c] = 0.f;
    const float* myrow = &sh[t * 130];
#pragma unroll 4
    for (int k = 0; k < 128; ++k) {
        float v = myrow[k];
#pragma unroll
        for (int c = 0; c < NCLASS; ++c)
            acc[c] = fmaf(v, w2s[c * 128 + k], acc[c]);
    }
    int rr = r0 + t;
    if (rr < N_NODES) {
#pragma unroll
        for (int c = 0; c < NCLASS; ++c) {
            float z = acc[c] + b2s[c];
            out[(size_t)rr * NCLASS + c] = 1.f / (1.f + expf(-z));
        }
    }
}

// ---------------- launcher ----------------
extern "C" void kernel_launch(void* const* d_in, const int* in_sizes, int n_in,
                              void* d_out, int out_size, void* d_ws, size_t ws_size,
                              hipStream_t stream) {
    const float* x     = (const float*)d_in[0];
    const int*   ei    = (const int*)d_in[1];
    const float* W1    = (const float*)d_in[2];
    const float* b1    = (const float*)d_in[3];
    const float* gamma = (const float*)d_in[4];
    const float* beta  = (const float*)d_in[5];
    const float* W2    = (const float*)d_in[6];
    const float* b2    = (const float*)d_in[7];
    const float* l1W   = (const float*)d_in[8];
    const float* l1b   = (const float*)d_in[9];
    const float* l2W   = (const float*)d_in[10];
    const float* l2b   = (const float*)d_in[11];
    float* out = (float*)d_out;

    char* w = (char*)d_ws;
    float*  zbuf   = (float*) (w);                   // 51,200,000 B fp32 z
    ushort* hbf    = (ushort*)(w + 51200000);        // 25,600,000 B bf16 h
    ushort* aggout = (ushort*)(w + 76800000);        // 25,600,000 B bf16 agg / lin1 out
    int*   row_ptr = (int*)   (w + 102400000);       // 400,004 B (reserve 400,640)
    int*   counts  = (int*)   (w + 102800640);       // 400,000 B
    int*   csr     = (int*)   (w + 103200640);       // 6,400,000 B
    int*   bsums   = (int*)   (w + 109600640);       // reserve 1024
    int*   boffs   = (int*)   (w + 109601664);       // reserve 1024
    float* gsum    = (float*) (w + 109602688);       // 128 f
    float* gsq     = gsum + 128;
    float* scale   = gsum + 256;
    float* shift   = gsum + 384;

    const int* src = ei;
    const int* dst = ei + N_EDGES;

    const int SCAN_NB = (N_NODES + 511) / 512;       // 196
    const int GEMM_NB = (N_NODES + 127) / 128;       // 782

    // ---- CSR build ----
    hipMemsetAsync(counts, 0, N_NODES * sizeof(int), stream);
    k_count<<<(N_EDGES + 255) / 256, 256, 0, stream>>>(dst, counts);
    k_scan_a<<<SCAN_NB, 256, 0, stream>>>(counts, bsums);
    k_scan_b<<<1, 256, 0, stream>>>(bsums, boffs, row_ptr, SCAN_NB);
    k_scan_c<<<SCAN_NB, 256, 0, stream>>>(counts, boffs, row_ptr);
    hipMemsetAsync(counts, 0, N_NODES * sizeof(int), stream);
    k_fill<<<(N_EDGES + 255) / 256, 256, 0, stream>>>(src, dst, row_ptr, counts, csr);

    // ---- x -> bf16 ----
    k_tobf16<<<(N_NODES * D / 4 + 255) / 256, 256, 0, stream>>>(x, hbf);

    // ---- 3 GIN layers ----
    for (int l = 0; l < NLAYERS; ++l) {
        k_aggregate<<<N_NODES / 4, 256, 0, stream>>>(hbf, row_ptr, csr, aggout);
        hipMemsetAsync(gsum, 0, 256 * sizeof(float), stream);
        // z = (h+agg) @ W1.T + b1  (fp32 out) + fused column stats
        k_gemm<0, 0, 0, 1><<<GEMM_NB, 256, 0, stream>>>(aggout, W1 + l * D * D, b1 + l * D,
                                                        nullptr, nullptr, zbuf, gsum, gsq, N_NODES);
        k_bnfin<<<1, 128, 0, stream>>>(gsum, gsq, gamma + l * D, beta + l * D, scale, shift);
        // h' = relu( relu(BN(z)) @ W2.T + b2 )  (bf16 out, in place over hbf)
        k_gemm<1, 1, 1, 0><<<GEMM_NB, 256, 0, stream>>>(zbuf, W2 + l * D * D, b2 + l * D,
                                                        scale, shift, hbf, nullptr, nullptr, N_NODES);
    }

    // ---- head ----
    k_gemm<0, 1, 1, 0><<<GEMM_NB, 256, 0, stream>>>(hbf, l1W, l1b, nullptr, nullptr,
                                                    aggout, nullptr, nullptr, N_NODES);
    k_head2<<<GEMM_NB, 128, 0, stream>>>(aggout, l2W, l2b, out);
}